// Round 1
// baseline (920.286 us; speedup 1.0000x reference)
//
#include <hip/hip_runtime.h>

// SoftCLDiceLoss fully fused: soft_skel (11 erode + 11 dilate steps, halo 12)
// computed per 64x64 tile entirely in LDS; per-(b,c) sums via atomics; tiny
// finalize kernel produces the scalar loss.

#define TILE 64
#define HALO 12
#define RDIM (TILE + 2 * HALO)   // 88
#define RAREA (RDIM * RDIM)      // 7744
#define IMG_H 1024
#define IMG_W 1024
#define NBC 16                   // B*C = 8*2
#define NITER 11                 // k = 0..10 (initial delta + 10 loop iters)
#define LEPS 1e-6f

__device__ __forceinline__ float min3f(float a, float b, float c) { return fminf(fminf(a, b), c); }
__device__ __forceinline__ float max3f(float a, float b, float c) { return fmaxf(fmaxf(a, b), c); }
__device__ __forceinline__ float sigmoidf(float x) { return 1.0f / (1.0f + __expf(-x)); }

__global__ __launch_bounds__(256)
void skel_tile_kernel(const float* __restrict__ pred,
                      const float* __restrict__ target,
                      float* __restrict__ ws)
{
    __shared__ __align__(16) float bufA[RAREA];
    __shared__ __align__(16) float bufB[RAREA];

    const int tid = threadIdx.x;
    const int bc  = blockIdx.z & (NBC - 1);
    const int img = blockIdx.z >> 4;          // 0: skel of sigmoid(pred), 1: skel of clip(target)
    const int r0  = blockIdx.y * TILE;
    const int c0  = blockIdx.x * TILE;

    const float* src = (img == 0) ? pred : target;
    const size_t base = (size_t)bc * (size_t)(IMG_H * IMG_W);

    // image-valid row bounds in buffer coords [0, RDIM)
    const int rLo  = max(0, HALO - r0);
    const int rHi  = min(RDIM - 1, (IMG_H - r0) + HALO - 1);
    const int rLoD = max(HALO - 1, rLo);              // dilate scratch row bounds
    const int rHiD = min(TILE + HALO, rHi);
    const bool leftEdge  = (c0 == 0);
    const bool rightEdge = (c0 + TILE == IMG_W);
    const bool anyEdge   = leftEdge || rightEdge;

    // ---- load region, replicate-clamped at image borders ----
    for (int idx = tid; idx < RAREA; idx += 256) {
        int rr = idx / RDIM;
        int cc = idx - rr * RDIM;
        int gr = min(max(r0 + rr - HALO, 0), IMG_H - 1);
        int gc = min(max(c0 + cc - HALO, 0), IMG_W - 1);
        float v = src[base + (size_t)gr * IMG_W + gc];
        v = (img == 0) ? sigmoidf(v) : fminf(fmaxf(v, 0.0f), 1.0f);
        bufA[idx] = v;
    }

    // each thread owns a 4x4 tile patch (16x16 patches = 256 threads)
    const int pr  = (tid >> 4) << 2;          // tile row 0..60
    const int pc  = (tid & 15) << 2;          // tile col 0..60
    const int prb = pr + HALO;                // buffer coords
    const int pcb = pc + HALO;

    float4 S[4];
#pragma unroll
    for (int r = 0; r < 4; ++r) S[r] = make_float4(0.f, 0.f, 0.f, 0.f);

    float* cur = bufA;   // e_k
    float* oth = bufB;

    for (int k = 0; k < NITER; ++k) {
        __syncthreads();

        // snapshot e_k at my patch (needed for delta after cur is trashed)
        float4 aP[4];
#pragma unroll
        for (int r = 0; r < 4; ++r)
            aP[r] = *(const float4*)&cur[(prb + r) * RDIM + pcb];

        // column-frame repair (replicate image edge) for L/R edge tiles
        if (leftEdge) {
            for (int i = tid; i < RDIM * HALO; i += 256) {
                int rr = i / HALO;
                int cc = i - rr * HALO;                       // 0..11
                cur[rr * RDIM + cc] = cur[rr * RDIM + HALO];
            }
        }
        if (rightEdge) {
            for (int i = tid; i < RDIM * HALO; i += 256) {
                int rr = i / HALO;
                int cc = i - rr * HALO;
                cur[rr * RDIM + (TILE + HALO) + cc] = cur[rr * RDIM + (TILE + HALO - 1)];
            }
        }
        if (anyEdge) __syncthreads();

        // ---- erode horizontal: cur -> oth, full region (88 rows x 22 col-groups) ----
        for (int idx = tid; idx < RDIM * (RDIM / 4); idx += 256) {
            int rr = idx / (RDIM / 4);
            int g  = idx - rr * (RDIM / 4);
            int c  = g << 2;
            int rowb = rr * RDIM;
            float4 v = *(const float4*)&cur[rowb + c];
            float lf = cur[rowb + max(c - 1, 0)];
            float rt = cur[rowb + min(c + 4, RDIM - 1)];
            float4 o;
            o.x = min3f(lf, v.x, v.y);
            o.y = min3f(v.x, v.y, v.z);
            o.z = min3f(v.y, v.z, v.w);
            o.w = min3f(v.z, v.w, rt);
            *(float4*)&oth[rowb + c] = o;
        }
        __syncthreads();

        // ---- erode vertical, in place on oth (register strips, read-all then write) ----
        {
            float4 vreg[10];
            int vs = tid / (RDIM / 4);        // 0..11
            int vg = tid - vs * (RDIM / 4);
            bool vact = (vs < 11);            // 11 strips x 8 rows = 88
            int vc = vg << 2;
            int vr = vs << 3;
            if (vact) {
#pragma unroll
                for (int r = 0; r < 10; ++r) {
                    int rr = min(max(vr + r - 1, rLo), rHi);   // image-row replicate
                    vreg[r] = *(const float4*)&oth[rr * RDIM + vc];
                }
            }
            __syncthreads();
            if (vact) {
#pragma unroll
                for (int r = 0; r < 8; ++r) {
                    float4 o;
                    o.x = min3f(vreg[r].x, vreg[r + 1].x, vreg[r + 2].x);
                    o.y = min3f(vreg[r].y, vreg[r + 1].y, vreg[r + 2].y);
                    o.z = min3f(vreg[r].z, vreg[r + 1].z, vreg[r + 2].z);
                    o.w = min3f(vreg[r].w, vreg[r + 1].w, vreg[r + 2].w);
                    *(float4*)&oth[(vr + r) * RDIM + vc] = o;
                }
            }
            __syncthreads();
        }
        // oth now holds e_{k+1}

        // column-frame repair on oth before dilate-H (edge tiles)
        if (leftEdge) {
            for (int i = tid; i < RDIM * HALO; i += 256) {
                int rr = i / HALO;
                int cc = i - rr * HALO;
                oth[rr * RDIM + cc] = oth[rr * RDIM + HALO];
            }
        }
        if (rightEdge) {
            for (int i = tid; i < RDIM * HALO; i += 256) {
                int rr = i / HALO;
                int cc = i - rr * HALO;
                oth[rr * RDIM + (TILE + HALO) + cc] = oth[rr * RDIM + (TILE + HALO - 1)];
            }
        }
        if (anyEdge) __syncthreads();

        // ---- dilate horizontal: oth -> cur (scratch), rows 11..76, tile cols ----
        for (int idx = tid; idx < 66 * 16; idx += 256) {
            int rr = idx >> 4;                       // 0..65
            int g  = idx & 15;
            int rowb = (rr + HALO - 1) * RDIM;       // buffer rows 11..76
            int c = (g << 2) + HALO;                 // buffer cols 12..72 (groups)
            float4 v = *(const float4*)&oth[rowb + c];
            float lf = oth[rowb + c - 1];
            float rt = oth[rowb + c + 4];
            float4 o;
            o.x = max3f(lf, v.x, v.y);
            o.y = max3f(v.x, v.y, v.z);
            o.z = max3f(v.y, v.z, v.w);
            o.w = max3f(v.z, v.w, rt);
            *(float4*)&cur[rowb + c] = o;
        }
        __syncthreads();

        // ---- dilate vertical + delta + skel update (registers only) ----
        {
            float4 dreg[6];
#pragma unroll
            for (int r = 0; r < 6; ++r) {
                int rr = min(max(prb + r - 1, rLoD), rHiD);   // image-row replicate
                dreg[r] = *(const float4*)&cur[rr * RDIM + pcb];
            }
#pragma unroll
            for (int r = 0; r < 4; ++r) {
                float4 d;
                d.x = max3f(dreg[r].x, dreg[r + 1].x, dreg[r + 2].x);
                d.y = max3f(dreg[r].y, dreg[r + 1].y, dreg[r + 2].y);
                d.z = max3f(dreg[r].z, dreg[r + 1].z, dreg[r + 2].z);
                d.w = max3f(dreg[r].w, dreg[r + 1].w, dreg[r + 2].w);
                float dx = fmaxf(aP[r].x - d.x, 0.0f);
                float dy = fmaxf(aP[r].y - d.y, 0.0f);
                float dz = fmaxf(aP[r].z - d.z, 0.0f);
                float dw = fmaxf(aP[r].w - d.w, 0.0f);
                S[r].x += fmaxf(dx - S[r].x * dx, 0.0f);
                S[r].y += fmaxf(dy - S[r].y * dy, 0.0f);
                S[r].z += fmaxf(dz - S[r].z * dz, 0.0f);
                S[r].w += fmaxf(dw - S[r].w * dw, 0.0f);
            }
        }

        { float* t_ = cur; cur = oth; oth = t_; }
    }

    // ---- tile sums: Σ skel and Σ skel * other ----
    const float* osrc = (img == 0) ? target : pred;
    float s_sum = 0.0f, sp_sum = 0.0f;
#pragma unroll
    for (int r = 0; r < 4; ++r) {
        float4 ov = *(const float4*)&osrc[base + (size_t)(r0 + pr + r) * IMG_W + (c0 + pc)];
        if (img == 1) {
            ov.x = sigmoidf(ov.x); ov.y = sigmoidf(ov.y);
            ov.z = sigmoidf(ov.z); ov.w = sigmoidf(ov.w);
        }
        s_sum  += (S[r].x + S[r].y) + (S[r].z + S[r].w);
        sp_sum += (S[r].x * ov.x + S[r].y * ov.y) + (S[r].z * ov.z + S[r].w * ov.w);
    }

    // block reduction: wave shuffle, then 4 wave partials through LDS
#pragma unroll
    for (int off = 32; off > 0; off >>= 1) {
        s_sum  += __shfl_down(s_sum,  off, 64);
        sp_sum += __shfl_down(sp_sum, off, 64);
    }
    __syncthreads();
    if ((tid & 63) == 0) {
        bufA[(tid >> 6) * 2 + 0] = sp_sum;
        bufA[(tid >> 6) * 2 + 1] = s_sum;
    }
    __syncthreads();
    if (tid == 0) {
        float a = (bufA[0] + bufA[2]) + (bufA[4] + bufA[6]);
        float b = (bufA[1] + bufA[3]) + (bufA[5] + bufA[7]);
        float* acc = ws + (size_t)blockIdx.z * 2;
        atomicAdd(acc + 0, a);   // Σ skel * other
        atomicAdd(acc + 1, b);   // Σ skel
    }
}

__global__ void finalize_kernel(const float* __restrict__ ws, float* __restrict__ out)
{
    if (threadIdx.x == 0) {
        float acc = 0.0f;
        for (int bc = 0; bc < NBC; ++bc) {
            float spt = ws[(0 * NBC + bc) * 2 + 0];  // Σ skel_p * t
            float sp  = ws[(0 * NBC + bc) * 2 + 1];  // Σ skel_p
            float stp = ws[(1 * NBC + bc) * 2 + 0];  // Σ skel_t * p
            float st  = ws[(1 * NBC + bc) * 2 + 1];  // Σ skel_t
            float tprec = spt / (sp + LEPS);
            float tsens = stp / (st + LEPS);
            float cl = 1.0f - 2.0f * tprec * tsens / (tprec + tsens + LEPS);
            acc += cl;
        }
        out[0] = acc / (float)NBC;
    }
}

extern "C" void kernel_launch(void* const* d_in, const int* in_sizes, int n_in,
                              void* d_out, int out_size, void* d_ws, size_t ws_size,
                              hipStream_t stream) {
    const float* pred   = (const float*)d_in[0];
    const float* target = (const float*)d_in[1];
    float* ws  = (float*)d_ws;
    float* out = (float*)d_out;

    hipMemsetAsync(d_ws, 0, 2 * NBC * 2 * sizeof(float), stream);

    dim3 grid(IMG_W / TILE, IMG_H / TILE, 2 * NBC);   // 16 x 16 x 32
    skel_tile_kernel<<<grid, 256, 0, stream>>>(pred, target, ws);
    finalize_kernel<<<1, 64, 0, stream>>>(ws, out);
}

// Round 2
// 678.211 us; speedup vs baseline: 1.3569x; 1.3569x over previous
//
#include <hip/hip_runtime.h>

// SoftCLDiceLoss fully fused, round 2:
//  - fused 2D erode (3x3 min) and fused 2D dilate+delta passes (no H/V
//    intermediate round-trips, no snapshot, 2 syncs/iter instead of ~6)
//  - all LDS traffic is lane-stride-16B float4 (conflict-free); neighbor
//    columns come from reading the adjacent float4 group (L.w / R.x)
//  - shrink-aware regions: e_{k+1} computed only on halo 11-k
//  - image-edge replicate via per-read row clamp + conditional col selects

#define TILE 64
#define HALO 12
#define RDIM (TILE + 2 * HALO)   // 88
#define RAREA (RDIM * RDIM)      // 7744
#define NGRP (RDIM / 4)          // 22
#define IMG_H 1024
#define IMG_W 1024
#define NBC 16                   // B*C
#define NITER 11                 // k = 0..10
#define LEPS 1e-6f

__device__ __forceinline__ float min3f(float a, float b, float c) { return fminf(fminf(a, b), c); }
__device__ __forceinline__ float max3f(float a, float b, float c) { return fmaxf(fmaxf(a, b), c); }
__device__ __forceinline__ float sigmoidf(float x) { return 1.0f / (1.0f + __expf(-x)); }

__global__ __launch_bounds__(256)
void skel_tile_kernel(const float* __restrict__ pred,
                      const float* __restrict__ target,
                      float* __restrict__ ws)
{
    __shared__ __align__(16) float bufA[RAREA];
    __shared__ __align__(16) float bufB[RAREA];

    const int tid = threadIdx.x;
    const int bc  = blockIdx.z & (NBC - 1);
    const int img = blockIdx.z >> 4;          // 0: skel(sigmoid(pred)), 1: skel(clip(target))
    const int r0  = blockIdx.y * TILE;
    const int c0  = blockIdx.x * TILE;

    const float* src = (img == 0) ? pred : target;
    const size_t base = (size_t)bc * (size_t)(IMG_H * IMG_W);

    // image-valid bounds in buffer coords (replicate-clamp targets)
    const int rLo = (r0 == 0) ? HALO : 0;
    const int rHi = (r0 + TILE == IMG_H) ? (TILE + HALO - 1) : (RDIM - 1);
    const int cLo = (c0 == 0) ? HALO : 0;
    const int cHi = (c0 + TILE == IMG_W) ? (TILE + HALO - 1) : (RDIM - 1);

    // ---- load 88x88 region (float4 groups, replicate-clamped at image borders) ----
    for (int idx = tid; idx < RDIM * NGRP; idx += 256) {
        int rr = idx / NGRP;
        int g  = idx - rr * NGRP;
        int gr = min(max(r0 + rr - HALO, 0), IMG_H - 1);
        int gcb = c0 + (g << 2) - HALO;
        const float* rowp = src + base + (size_t)gr * IMG_W;
        float4 v;
        if (gcb >= 0 && gcb + 4 <= IMG_W) {
            v = *(const float4*)(rowp + gcb);
        } else {
            v.x = rowp[min(max(gcb + 0, 0), IMG_W - 1)];
            v.y = rowp[min(max(gcb + 1, 0), IMG_W - 1)];
            v.z = rowp[min(max(gcb + 2, 0), IMG_W - 1)];
            v.w = rowp[min(max(gcb + 3, 0), IMG_W - 1)];
        }
        if (img == 0) {
            v.x = sigmoidf(v.x); v.y = sigmoidf(v.y);
            v.z = sigmoidf(v.z); v.w = sigmoidf(v.w);
        } else {
            v.x = fminf(fmaxf(v.x, 0.f), 1.f); v.y = fminf(fmaxf(v.y, 0.f), 1.f);
            v.z = fminf(fmaxf(v.z, 0.f), 1.f); v.w = fminf(fmaxf(v.w, 0.f), 1.f);
        }
        *(float4*)&bufA[rr * RDIM + (g << 2)] = v;
    }

    // per-thread 4x4 output patch (for dilate+delta and final sums)
    const int pr  = (tid >> 4) << 2;
    const int pc  = (tid & 15) << 2;
    const int prb = pr + HALO;
    const int pcb = pc + HALO;
    const int gp  = pcb >> 2;                 // 3..18

    float4 S[4];
#pragma unroll
    for (int r = 0; r < 4; ++r) S[r] = make_float4(0.f, 0.f, 0.f, 0.f);

    float* cur = bufA;   // e_k
    float* oth = bufB;

    for (int k = 0; k < NITER; ++k) {
        __syncthreads();

        // ---- fused erode 3x3: cur -> oth on shrink-aware region ----
        {
            const int r_base = 1 + k;
            const int r_hiK  = 86 - k;
            const int g_loK  = (1 + k) >> 2;
            const int g_hiK  = (86 - k) >> 2;
            const int ng     = g_hiK - g_loK + 1;
            const int ns     = ((r_hiK - r_base + 1) + 7) >> 3;   // 8-row strips
            const int cnt    = ns * ng;

            if (tid < cnt) {
                const int s  = tid / ng;
                const int g  = g_loK + (tid - s * ng);
                const int rb0 = r_base + (s << 3);
                const int gm  = max(g - 1, 0);
                const int gq  = min(g + 1, NGRP - 1);
                const bool lsel = ((g << 2) <= cLo);
                const bool rsel = ((g << 2) + 4 > cHi);

                float4 h[10];
#pragma unroll
                for (int j = 0; j < 10; ++j) {
                    int rr = min(max(rb0 - 1 + j, rLo), rHi);
                    const float* rp = cur + rr * RDIM;
                    float4 M = *(const float4*)(rp + (g << 2));
                    float4 L = *(const float4*)(rp + (gm << 2));
                    float4 R = *(const float4*)(rp + (gq << 2));
                    float lf = lsel ? M.x : L.w;
                    float rt = rsel ? M.w : R.x;
                    h[j].x = min3f(lf, M.x, M.y);
                    h[j].y = min3f(M.x, M.y, M.z);
                    h[j].z = min3f(M.y, M.z, M.w);
                    h[j].w = min3f(M.z, M.w, rt);
                }
#pragma unroll
                for (int j = 0; j < 8; ++j) {
                    int r = rb0 + j;
                    if (r <= r_hiK) {
                        float4 o;
                        o.x = min3f(h[j].x, h[j + 1].x, h[j + 2].x);
                        o.y = min3f(h[j].y, h[j + 1].y, h[j + 2].y);
                        o.z = min3f(h[j].z, h[j + 1].z, h[j + 2].z);
                        o.w = min3f(h[j].w, h[j + 1].w, h[j + 2].w);
                        *(float4*)&oth[r * RDIM + (g << 2)] = o;
                    }
                }
            }
        }
        __syncthreads();

        // ---- fused dilate 3x3 + delta + skel update (oth = e_{k+1}) ----
        {
            // e_k values at my patch (cur is intact — ping-pong)
            float4 aP[4];
#pragma unroll
            for (int r = 0; r < 4; ++r)
                aP[r] = *(const float4*)&cur[(prb + r) * RDIM + pcb];

            const bool lsel = ((gp << 2) <= cLo);        // only gp==3 on left-edge tiles
            const bool rsel = ((gp << 2) + 4 > cHi);     // only gp==18 on right-edge tiles

            float4 hm[6];
#pragma unroll
            for (int j = 0; j < 6; ++j) {
                int rr = min(max(prb - 1 + j, rLo), rHi);
                const float* rp = oth + rr * RDIM;
                float4 M = *(const float4*)(rp + (gp << 2));
                float4 L = *(const float4*)(rp + ((gp - 1) << 2));
                float4 R = *(const float4*)(rp + ((gp + 1) << 2));
                float lf = lsel ? M.x : L.w;
                float rt = rsel ? M.w : R.x;
                hm[j].x = max3f(lf, M.x, M.y);
                hm[j].y = max3f(M.x, M.y, M.z);
                hm[j].z = max3f(M.y, M.z, M.w);
                hm[j].w = max3f(M.z, M.w, rt);
            }
#pragma unroll
            for (int r = 0; r < 4; ++r) {
                float4 d;
                d.x = max3f(hm[r].x, hm[r + 1].x, hm[r + 2].x);
                d.y = max3f(hm[r].y, hm[r + 1].y, hm[r + 2].y);
                d.z = max3f(hm[r].z, hm[r + 1].z, hm[r + 2].z);
                d.w = max3f(hm[r].w, hm[r + 1].w, hm[r + 2].w);
                float dx = fmaxf(aP[r].x - d.x, 0.0f);
                float dy = fmaxf(aP[r].y - d.y, 0.0f);
                float dz = fmaxf(aP[r].z - d.z, 0.0f);
                float dw = fmaxf(aP[r].w - d.w, 0.0f);
                S[r].x += fmaxf(dx - S[r].x * dx, 0.0f);
                S[r].y += fmaxf(dy - S[r].y * dy, 0.0f);
                S[r].z += fmaxf(dz - S[r].z * dz, 0.0f);
                S[r].w += fmaxf(dw - S[r].w * dw, 0.0f);
            }
        }

        { float* t_ = cur; cur = oth; oth = t_; }
    }

    // ---- tile sums: Σ skel and Σ skel * other ----
    const float* osrc = (img == 0) ? target : pred;
    float s_sum = 0.0f, sp_sum = 0.0f;
#pragma unroll
    for (int r = 0; r < 4; ++r) {
        float4 ov = *(const float4*)&osrc[base + (size_t)(r0 + pr + r) * IMG_W + (c0 + pc)];
        if (img == 1) {
            ov.x = sigmoidf(ov.x); ov.y = sigmoidf(ov.y);
            ov.z = sigmoidf(ov.z); ov.w = sigmoidf(ov.w);
        }
        s_sum  += (S[r].x + S[r].y) + (S[r].z + S[r].w);
        sp_sum += (S[r].x * ov.x + S[r].y * ov.y) + (S[r].z * ov.z + S[r].w * ov.w);
    }

#pragma unroll
    for (int off = 32; off > 0; off >>= 1) {
        s_sum  += __shfl_down(s_sum,  off, 64);
        sp_sum += __shfl_down(sp_sum, off, 64);
    }
    __syncthreads();
    if ((tid & 63) == 0) {
        bufA[(tid >> 6) * 2 + 0] = sp_sum;
        bufA[(tid >> 6) * 2 + 1] = s_sum;
    }
    __syncthreads();
    if (tid == 0) {
        float a = (bufA[0] + bufA[2]) + (bufA[4] + bufA[6]);
        float b = (bufA[1] + bufA[3]) + (bufA[5] + bufA[7]);
        float* acc = ws + (size_t)blockIdx.z * 2;
        atomicAdd(acc + 0, a);   // Σ skel * other
        atomicAdd(acc + 1, b);   // Σ skel
    }
}

__global__ void finalize_kernel(const float* __restrict__ ws, float* __restrict__ out)
{
    if (threadIdx.x == 0) {
        float acc = 0.0f;
        for (int bc = 0; bc < NBC; ++bc) {
            float spt = ws[(0 * NBC + bc) * 2 + 0];
            float sp  = ws[(0 * NBC + bc) * 2 + 1];
            float stp = ws[(1 * NBC + bc) * 2 + 0];
            float st  = ws[(1 * NBC + bc) * 2 + 1];
            float tprec = spt / (sp + LEPS);
            float tsens = stp / (st + LEPS);
            float cl = 1.0f - 2.0f * tprec * tsens / (tprec + tsens + LEPS);
            acc += cl;
        }
        out[0] = acc / (float)NBC;
    }
}

extern "C" void kernel_launch(void* const* d_in, const int* in_sizes, int n_in,
                              void* d_out, int out_size, void* d_ws, size_t ws_size,
                              hipStream_t stream) {
    const float* pred   = (const float*)d_in[0];
    const float* target = (const float*)d_in[1];
    float* ws  = (float*)d_ws;
    float* out = (float*)d_out;

    hipMemsetAsync(d_ws, 0, 2 * NBC * 2 * sizeof(float), stream);

    dim3 grid(IMG_W / TILE, IMG_H / TILE, 2 * NBC);   // 16 x 16 x 32
    skel_tile_kernel<<<grid, 256, 0, stream>>>(pred, target, ws);
    finalize_kernel<<<1, 64, 0, stream>>>(ws, out);
}